// Round 7
// baseline (1119.308 us; speedup 1.0000x reference)
//
#include <hip/hip_runtime.h>
#include <math.h>

#define NB 64
#define NC 512
#define NHW 4096
#define NHID 32
#define GRID 256
#define BLK 512
#define CHUNK 8
#define NCHUNKS (NB / CHUNK)      // 8

typedef float f32x4 __attribute__((ext_vector_type(4)));

// Device-scope grid barrier, generation k = 1,2,... cnt/rel zeroed per launch.
__device__ __forceinline__ void gbar(unsigned* cnt, unsigned* rel, unsigned k) {
    __threadfence();                       // release this thread's writes device-wide
    __syncthreads();
    if (threadIdx.x == 0) {
        unsigned old = atomicAdd(cnt, 1u); // device-scope
        if (old == k * GRID - 1u) {
            __hip_atomic_store(rel, k, __ATOMIC_RELEASE, __HIP_MEMORY_SCOPE_AGENT);
        } else {
            while (__hip_atomic_load(rel, __ATOMIC_ACQUIRE,
                                     __HIP_MEMORY_SCOPE_AGENT) < k) {
                __builtin_amdgcn_s_sleep(2);
            }
        }
    }
    __syncthreads();
}

// One block per CU (256 blocks x 512 threads). Block blk owns channels
// {2*blk, 2*blk+1} of every sample. Per 8-sample chunk: x -> registers
// (4 x float4 per sample per thread), pool-reduce -> y, grid barrier,
// redundant per-block MLP for its 2 channels, scale registers, nt-store.
// x is read from HBM exactly once.
__global__ __launch_bounds__(BLK, 2) void fused_kernel(
        const float* __restrict__ x,
        const int* __restrict__ dataset,
        const float* __restrict__ W1,
        const float* __restrict__ W2,
        float* __restrict__ out,
        float* __restrict__ y,
        unsigned* __restrict__ cnt,
        unsigned* __restrict__ rel) {
    const int tid  = threadIdx.x;
    const int blk  = blockIdx.x;
    const int half = tid >> 8;            // which of the block's 2 channels
    const int l256 = tid & 255;
    const int wid  = tid >> 6;            // 0..7
    const int lane = tid & 63;
    const int c0   = blk * 2;

    __shared__ float ysl[CHUNK * NC];     // 16 KiB
    __shared__ float hsl[CHUNK * NHID];   // 1 KiB
    __shared__ float gsl[CHUNK * 2];
    __shared__ float part[8][CHUNK];
    __shared__ int   esl[CHUNK];

    const f32x4* __restrict__ x4 = reinterpret_cast<const f32x4*>(x);
    f32x4* __restrict__ o4 = reinterpret_cast<f32x4*>(out);

    for (int ci = 0; ci < NCHUNKS; ++ci) {
        const int b0 = ci * CHUNK;

        // ---- load chunk into registers + pool ----
        f32x4 v[CHUNK][4];
        size_t pbase[CHUNK];
#pragma unroll
        for (int s = 0; s < CHUNK; ++s) {
            pbase[s] = (((size_t)(b0 + s) * NC + c0 + half) << 10) + l256;
#pragma unroll
            for (int k = 0; k < 4; ++k)
                v[s][k] = x4[pbase[s] + (k << 8)];
        }
#pragma unroll
        for (int s = 0; s < CHUNK; ++s) {
            f32x4 a = v[s][0] + v[s][1] + v[s][2] + v[s][3];
            float t = a.x + a.y + a.z + a.w;
#pragma unroll
            for (int o = 32; o; o >>= 1) t += __shfl_down(t, o, 64);
            if (lane == 0) part[wid][s] = t;
        }
        __syncthreads();
        if (tid < CHUNK * 2) {                   // 16 threads write y
            const int s = tid >> 1, h = tid & 1;
            float t = part[h * 4 + 0][s] + part[h * 4 + 1][s] +
                      part[h * 4 + 2][s] + part[h * 4 + 3][s];
            y[(b0 + s) * NC + c0 + h] = t * (1.0f / NHW);
        }

        // ---- grid barrier: all pools of this chunk complete ----
        gbar(cnt, rel, (unsigned)(ci + 1));

        // ---- gate MLP (redundant per block; coherent agent-scope y reads) ----
        if (tid < CHUNK) esl[tid] = dataset[b0 + tid];
        for (int i = tid; i < CHUNK * NC; i += BLK) {
            const int s = i >> 9, c = i & (NC - 1);
            ysl[i] = __hip_atomic_load(&y[(b0 + s) * NC + c],
                                       __ATOMIC_RELAXED, __HIP_MEMORY_SCOPE_AGENT);
        }
        __syncthreads();
        {
            const int hid = tid >> 4, j = tid & 15;   // 16 lanes per hidden unit
            for (int s = 0; s < CHUNK; ++s) {
                const float* __restrict__ w1row =
                    W1 + ((size_t)esl[s] * NHID + hid) * NC;
                float acc = 0.f;
                for (int c = j; c < NC; c += 16) acc += ysl[s * NC + c] * w1row[c];
#pragma unroll
                for (int o = 8; o; o >>= 1) acc += __shfl_down(acc, o, 16);
                if (j == 0) hsl[s * NHID + hid] = fmaxf(acc, 0.f);
            }
        }
        __syncthreads();
        if (tid < CHUNK * 2) {                   // 16 gates (2 channels x 8 samples)
            const int s = tid >> 1, ch = tid & 1;
            const float* __restrict__ w2row =
                W2 + ((size_t)esl[s] * NC + c0 + ch) * NHID;
            float z = 0.f;
#pragma unroll
            for (int h = 0; h < NHID; ++h) z += hsl[s * NHID + h] * w2row[h];
            gsl[tid] = 1.0f / (1.0f + expf(-z));
        }
        __syncthreads();

        // ---- scale registers + nt-store ----
#pragma unroll
        for (int s = 0; s < CHUNK; ++s) {
            const float g = gsl[s * 2 + half];
#pragma unroll
            for (int k = 0; k < 4; ++k) {
                f32x4 w = v[s][k] * g;
                __builtin_nontemporal_store(w, &o4[pbase[s] + (k << 8)]);
            }
        }
    }
}

extern "C" void kernel_launch(void* const* d_in, const int* in_sizes, int n_in,
                              void* d_out, int out_size, void* d_ws, size_t ws_size,
                              hipStream_t stream) {
    const float* x       = (const float*)d_in[0];
    const int*   dataset = (const int*)d_in[1];
    const float* W1      = (const float*)d_in[2];
    const float* W2      = (const float*)d_in[3];
    float* out = (float*)d_out;

    unsigned* cnt = (unsigned*)d_ws;                       // [0]
    unsigned* rel = cnt + 1;                               // [1]
    float*    y   = (float*)((char*)d_ws + 256);           // NB*NC floats

    hipMemsetAsync(d_ws, 0, 256, stream);                  // reset barrier state
    fused_kernel<<<GRID, BLK, 0, stream>>>(x, dataset, W1, W2, out, y, cnt, rel);
}